// Round 2
// baseline (3070.046 us; speedup 1.0000x reference)
//
#include <hip/hip_runtime.h>
#include <cstdio>

// Problem constants
constexpr int    kTokens = 50176;                       // B*nW*N = 16*64*49
constexpr size_t TCsz    = (size_t)kTokens * 256;       // 12,845,056 elements
constexpr size_t SSsz    = (size_t)1024 * 8 * 49 * 49;  // 19,668,992 elements
constexpr float  kScale  = 0.17677669529663687f;        // 32^-0.5

// ---------------- block reduce (sum, sumsq) over 256 threads ----------------
__device__ __forceinline__ float2 block_sum2(float s, float s2, float* sbuf) {
#pragma unroll
  for (int off = 32; off > 0; off >>= 1) {
    s  += __shfl_down(s,  off);
    s2 += __shfl_down(s2, off);
  }
  int wv = threadIdx.x >> 6;
  if ((threadIdx.x & 63) == 0) { sbuf[wv * 2] = s; sbuf[wv * 2 + 1] = s2; }
  __syncthreads();
  s  = sbuf[0] + sbuf[2] + sbuf[4] + sbuf[6];
  s2 = sbuf[1] + sbuf[3] + sbuf[5] + sbuf[7];
  return make_float2(s, s2);
}

// ---------------- K1: LN1 + roll(-3,-3) + window partition ----------------
// one block per OUTPUT window-token t = (b*64+win)*49 + n ; 256 threads = channels
__global__ __launch_bounds__(256) void pre_ln_k(const float* __restrict__ x,
                                                const float* __restrict__ g,
                                                const float* __restrict__ b,
                                                float* __restrict__ xw) {
  __shared__ float sbuf[8];
  int t = blockIdx.x, c = threadIdx.x;
  int bb = t / 3136, r = t % 3136;
  int wi = r / 49, n = r % 49;
  int hp = (wi >> 3) * 7 + n / 7;   // shifted spatial row h'
  int wp = (wi & 7) * 7 + n % 7;    // shifted spatial col w'
  int sh = hp + 3; if (sh >= 56) sh -= 56;   // roll(-3): xs[h'] = x[(h'+3)%56]
  int sw = wp + 3; if (sw >= 56) sw -= 56;
  float v = x[((size_t)bb * 3136 + sh * 56 + sw) * 256 + c];
  float2 ss = block_sum2(v, v * v, sbuf);
  float mean = ss.x * (1.0f / 256.0f);
  float var  = ss.y * (1.0f / 256.0f) - mean * mean;
  float rstd = rsqrtf(var + 1e-5f);
  xw[(size_t)t * 256 + c] = (v - mean) * rstd * g[c] + b[c];
}

// ---------------- LN2 (identity spatial mapping) ----------------
__global__ __launch_bounds__(256) void ln2_k(const float* __restrict__ xr,
                                             const float* __restrict__ g,
                                             const float* __restrict__ b,
                                             float* __restrict__ y) {
  __shared__ float sbuf[8];
  int t = blockIdx.x, c = threadIdx.x;
  float v = xr[(size_t)t * 256 + c];
  float2 ss = block_sum2(v, v * v, sbuf);
  float mean = ss.x * (1.0f / 256.0f);
  float var  = ss.y * (1.0f / 256.0f) - mean * mean;
  float rstd = rsqrtf(var + 1e-5f);
  y[(size_t)t * 256 + c] = (v - mean) * rstd * g[c] + b[c];
}

// ---------------- register-tiled fp32 GEMM: out = A(M x K) @ W(N x K)^T ----------------
// BM=BN=64, BK=16, 256 threads, 4x4 acc/thread. MODE selects epilogue.
// MODE 0: QKV scatter (+bias, q*scale) -> qkv buffer [which][win*8+head][n][d]
// MODE 1: proj: +bias, window-reverse + roll(+3) scatter, += aux(x) -> out(xr)
// MODE 2: fc1: +bias, exact GELU -> out[row*Nc+col]
// MODE 3: fc2: +bias, += aux(xr) -> out[row*256+col]
template <int MODE>
__global__ __launch_bounds__(256) void gemm_k(const float* __restrict__ A,
                                              const float* __restrict__ W,
                                              const float* __restrict__ bias,
                                              float* __restrict__ out,
                                              const float* __restrict__ aux,
                                              int K, int Nc) {
  __shared__ float As[16 * 68];  // [kk][m] padded stride 68
  __shared__ float Bs[16 * 68];  // [kk][n]
  const int tid  = threadIdx.x;
  const int m0   = blockIdx.y * 64;
  const int n0   = blockIdx.x * 64;
  const int tx   = tid & 15, ty = tid >> 4;
  const int lrow = tid >> 2;            // 0..63
  const int lcol = (tid & 3) << 2;      // 0,4,8,12
  float acc[4][4] = {};
  const float* Ap = A + (size_t)(m0 + lrow) * K + lcol;
  const float* Wp = W + (size_t)(n0 + lrow) * K + lcol;

  for (int k0 = 0; k0 < K; k0 += 16) {
    float4 av = *(const float4*)(Ap + k0);
    float4 bv = *(const float4*)(Wp + k0);
    As[(lcol + 0) * 68 + lrow] = av.x;
    As[(lcol + 1) * 68 + lrow] = av.y;
    As[(lcol + 2) * 68 + lrow] = av.z;
    As[(lcol + 3) * 68 + lrow] = av.w;
    Bs[(lcol + 0) * 68 + lrow] = bv.x;
    Bs[(lcol + 1) * 68 + lrow] = bv.y;
    Bs[(lcol + 2) * 68 + lrow] = bv.z;
    Bs[(lcol + 3) * 68 + lrow] = bv.w;
    __syncthreads();
#pragma unroll
    for (int kk = 0; kk < 16; ++kk) {
      const float4 a4 = *(const float4*)&As[kk * 68 + (ty << 2)];
      const float4 b4 = *(const float4*)&Bs[kk * 68 + (tx << 2)];
      const float a[4] = {a4.x, a4.y, a4.z, a4.w};
      const float bb[4] = {b4.x, b4.y, b4.z, b4.w};
#pragma unroll
      for (int i = 0; i < 4; ++i)
#pragma unroll
        for (int j = 0; j < 4; ++j) acc[i][j] = fmaf(a[i], bb[j], acc[i][j]);
    }
    __syncthreads();
  }

#pragma unroll
  for (int i = 0; i < 4; ++i) {
    const int row = m0 + (ty << 2) + i;
#pragma unroll
    for (int j = 0; j < 4; ++j) {
      const int col = n0 + (tx << 2) + j;
      float val = acc[i][j] + bias[col];
      if (MODE == 0) {
        const int which = col >> 8, head = (col >> 5) & 7, d = col & 31;
        if (which == 0) val *= kScale;
        const int wi = row / 49, n = row % 49;
        out[(size_t)which * TCsz + (size_t)(wi * 8 + head) * 1568 + n * 32 + d] = val;
      } else if (MODE == 1) {
        const int wi = row / 49, n = row % 49;
        const int b = wi >> 6, wl = wi & 63;
        const int hp = (wl >> 3) * 7 + n / 7;
        const int wp = (wl & 7) * 7 + n % 7;
        int h = hp + 3; if (h >= 56) h -= 56;  // roll(+3)
        int w = wp + 3; if (w >= 56) w -= 56;
        const size_t idx = ((size_t)(b * 3136 + h * 56 + w)) * 256 + col;
        out[idx] = aux[idx] + val;
      } else if (MODE == 2) {
        val = 0.5f * val * (1.0f + erff(val * 0.70710678118654752f));
        out[(size_t)row * Nc + col] = val;
      } else {
        const size_t idx = (size_t)row * 256 + col;
        out[idx] = aux[idx] + val;
      }
    }
  }
}

// ---------------- scores S = q@k^T + rpb + shift-mask, per (win, head) ----------------
__device__ __forceinline__ int lab3(int p) { return p < 49 ? 0 : (p < 53 ? 1 : 2); }

__global__ __launch_bounds__(256) void scores_k(const float* __restrict__ qkv,
                                                const float* __restrict__ rpb,
                                                float* __restrict__ S) {
  __shared__ float ql[49 * 33], kl[49 * 33];
  const int wi = blockIdx.x >> 3, head = blockIdx.x & 7;
  const float* qb = qkv + (size_t)blockIdx.x * 1568;          // q (pre-scaled)
  const float* kb = qkv + TCsz + (size_t)blockIdx.x * 1568;   // k
  for (int e = threadIdx.x; e < 1568; e += 256) {
    int i = e >> 5, d = e & 31;
    ql[i * 33 + d] = qb[e];
    kl[i * 33 + d] = kb[e];
  }
  __syncthreads();
  const int wl = wi & 63, wh = wl >> 3, ww = wl & 7;
  for (int e = threadIdx.x; e < 2401; e += 256) {
    const int i = e / 49, j = e % 49;
    float acc = 0.0f;
#pragma unroll
    for (int d = 0; d < 32; ++d) acc = fmaf(ql[i * 33 + d], kl[j * 33 + d], acc);
    const int yi = i / 7, xi = i % 7, yj = j / 7, xj = j % 7;
    acc += rpb[((yi - yj + 6) * 13 + (xi - xj + 6)) * 8 + head];
    const int li = lab3(wh * 7 + yi) * 3 + lab3(ww * 7 + xi);
    const int lj = lab3(wh * 7 + yj) * 3 + lab3(ww * 7 + xj);
    if (li != lj) acc -= 100.0f;
    S[(size_t)blockIdx.x * 2401 + e] = acc;
  }
}

// ---------------- head-fusion gate + softmax (both branches, in-place) ----------------
// one block (1 wave) per (win, n) query row; all 8 heads coupled by the 1x1-conv gate
__global__ __launch_bounds__(64) void fuse_softmax_k(float* __restrict__ S,
                                                     float* __restrict__ Ss,
                                                     const float* __restrict__ fw,
                                                     const float* __restrict__ fb) {
  __shared__ float s[8][49], ss[8][49];
  const int wi = blockIdx.x / 49, n = blockIdx.x % 49;
  const int tid = threadIdx.x;
  const size_t base = (size_t)wi * 8 * 2401 + (size_t)n * 49;
  for (int e = tid; e < 392; e += 64) {
    const int h = e / 49, m = e % 49;
    s[h][m]  = S[base + (size_t)h * 2401 + m];
    ss[h][m] = Ss[base + (size_t)h * 2401 + m];
  }
  __syncthreads();
  if (tid < 49) {
    const int m = tid;
    float diff[8], logit[8];
#pragma unroll
    for (int h = 0; h < 8; ++h) diff[h] = ss[h][m] - s[h][m];
#pragma unroll
    for (int o = 0; o < 8; ++o) {
      float g = fb[o];
#pragma unroll
      for (int h = 0; h < 8; ++h) g = fmaf(fw[o * 8 + h], diff[h], g);
      g = 1.0f / (1.0f + expf(-g));
      logit[o] = s[o][m] + diff[o] * g;
    }
#pragma unroll
    for (int o = 0; o < 8; ++o) s[o][m] = logit[o];
  }
  __syncthreads();
  // softmax over m for each head; 8 threads per head
  const int h = tid >> 3, sub = tid & 7;
  float mx = -1e30f, mxs = -1e30f;
  for (int m = sub; m < 49; m += 8) { mx = fmaxf(mx, s[h][m]); mxs = fmaxf(mxs, ss[h][m]); }
#pragma unroll
  for (int off = 4; off > 0; off >>= 1) {
    mx  = fmaxf(mx,  __shfl_down(mx,  off, 8));
    mxs = fmaxf(mxs, __shfl_down(mxs, off, 8));
  }
  mx  = __shfl(mx, 0, 8);
  mxs = __shfl(mxs, 0, 8);
  float sm = 0.0f, sms = 0.0f;
  for (int m = sub; m < 49; m += 8) { sm += expf(s[h][m] - mx); sms += expf(ss[h][m] - mxs); }
#pragma unroll
  for (int off = 4; off > 0; off >>= 1) {
    sm  += __shfl_down(sm,  off, 8);
    sms += __shfl_down(sms, off, 8);
  }
  sm  = __shfl(sm, 0, 8);
  sms = __shfl(sms, 0, 8);
  const float inv = 1.0f / sm, invs = 1.0f / sms;
  for (int m = sub; m < 49; m += 8) {
    S[base + (size_t)h * 2401 + m]  = expf(s[h][m] - mx) * inv;
    Ss[base + (size_t)h * 2401 + m] = expf(ss[h][m] - mxs) * invs;
  }
}

// ---------------- O = P @ V per (win, head); O stored token-major (t, head*32+d) ----------
__global__ __launch_bounds__(256) void pv_k(const float* __restrict__ P,
                                            const float* __restrict__ v,
                                            float* __restrict__ O) {
  __shared__ float pl[49 * 49], vl[49 * 32];
  const int wi = blockIdx.x >> 3, head = blockIdx.x & 7;
  const float* Pb = P + (size_t)blockIdx.x * 2401;
  const float* vb = v + (size_t)blockIdx.x * 1568;
  for (int e = threadIdx.x; e < 2401; e += 256) pl[e] = Pb[e];
  for (int e = threadIdx.x; e < 1568; e += 256) vl[e] = vb[e];
  __syncthreads();
  for (int e = threadIdx.x; e < 1568; e += 256) {
    const int nn = e >> 5, d = e & 31;
    float acc = 0.0f;
#pragma unroll
    for (int m = 0; m < 49; ++m) acc = fmaf(pl[nn * 49 + m], vl[m * 32 + d], acc);
    const int t = wi * 49 + nn;
    O[(size_t)t * 256 + head * 32 + d] = acc;
  }
}

extern "C" void kernel_launch(void* const* d_in, const int* in_sizes, int n_in,
                              void* d_out, int out_size, void* d_ws, size_t ws_size,
                              hipStream_t stream) {
  if (n_in < 29) { fprintf(stderr, "kernel_launch: expected 29 inputs, got %d\n", n_in); return; }
  const float* x      = (const float*)d_in[0];
  const float* xsar   = (const float*)d_in[1];
  const float* ln1_g  = (const float*)d_in[2];
  const float* ln1_b  = (const float*)d_in[3];
  const float* ln1s_g = (const float*)d_in[4];
  const float* ln1s_b = (const float*)d_in[5];
  const float* qkv_w  = (const float*)d_in[6];
  const float* qkv_b  = (const float*)d_in[7];
  const float* qkvs_w = (const float*)d_in[8];
  const float* qkvs_b = (const float*)d_in[9];
  const float* rpb    = (const float*)d_in[10];
  const float* fuse_w = (const float*)d_in[11];
  const float* fuse_b = (const float*)d_in[12];
  const float* proj_w = (const float*)d_in[13];
  const float* proj_b = (const float*)d_in[14];
  const float* projs_w = (const float*)d_in[15];
  const float* projs_b = (const float*)d_in[16];
  const float* ln2_g  = (const float*)d_in[17];
  const float* ln2_b  = (const float*)d_in[18];
  const float* ln2s_g = (const float*)d_in[19];
  const float* ln2s_b = (const float*)d_in[20];
  const float* fc1_w  = (const float*)d_in[21];
  const float* fc1_b  = (const float*)d_in[22];
  const float* fc2_w  = (const float*)d_in[23];
  const float* fc2_b  = (const float*)d_in[24];
  const float* fc1s_w = (const float*)d_in[25];
  const float* fc1s_b = (const float*)d_in[26];
  const float* fc2s_w = (const float*)d_in[27];
  const float* fc2s_b = (const float*)d_in[28];
  float* out = (float*)d_out;
  float* ws  = (float*)d_ws;

  // Workspace budget: harness provides exactly 8*TCsz floats (411 MB).
  const size_t need = 8 * TCsz * sizeof(float);
  if (ws_size < need) {
    fprintf(stderr, "kernel_launch: ws_size %zu < needed %zu\n", ws_size, need);
    return;
  }

  // --- Liveness-packed layout (units of TCsz floats within ws) ---
  // Phase QKV:     xw=ws0, xws=ws1 -> q=ws2,k=ws3,v=ws4, qs=ws5,ks=ws6,vs=ws7
  // Phase scores:  S_A -> d_out (1.53 TC <= 2 TC, dead before final writes)
  //                S_B -> ws0 (spans ws0..1.53; xw/xws dead)
  // Phase pv:      O=ws2 (q dead), Os=ws5 (qs dead)
  // Phase proj:    xr=ws3 (k dead), xrs=ws6 (ks dead)
  // Phase LN2:     y=ws0, ys=ws1 (scores dead after pv)
  // Phase MLP:     hbuf = ws4..ws6 (2 TC; v,Os dead), token-split into 2 halves
  float* xw   = ws;
  float* xws  = ws + TCsz;
  float* qkv  = ws + 2 * TCsz;     // q,k,v
  float* qkvs = ws + 5 * TCsz;     // qs,ks,vs
  float* S    = out;               // branch-A scores/P in d_out scratch
  float* Ssb  = ws;                // branch-B scores/P
  float* O    = ws + 2 * TCsz;
  float* Os   = ws + 5 * TCsz;
  float* xr   = ws + 3 * TCsz;
  float* xrs  = ws + 6 * TCsz;
  float* y    = ws;
  float* ysb  = ws + TCsz;
  float* hbuf = ws + 4 * TCsz;     // 2 TC (25088 tokens x 1024)

  // 1. LN1 + shift + window partition
  pre_ln_k<<<kTokens, 256, 0, stream>>>(x, ln1_g, ln1_b, xw);
  pre_ln_k<<<kTokens, 256, 0, stream>>>(xsar, ln1s_g, ln1s_b, xws);
  // 2. QKV GEMM (q pre-scaled), scatter to (win,head,n,d)
  gemm_k<0><<<dim3(12, 784), 256, 0, stream>>>(xw,  qkv_w,  qkv_b,  qkv,  nullptr, 256, 768);
  gemm_k<0><<<dim3(12, 784), 256, 0, stream>>>(xws, qkvs_w, qkvs_b, qkvs, nullptr, 256, 768);
  // 3. scores + rpb + shift mask   (branch A scores live in d_out as scratch)
  scores_k<<<8192, 256, 0, stream>>>(qkv,  rpb, S);
  scores_k<<<8192, 256, 0, stream>>>(qkvs, rpb, Ssb);
  // 4. dual-branch gate fusion + softmax (in place)
  fuse_softmax_k<<<1024 * 49, 64, 0, stream>>>(S, Ssb, fuse_w, fuse_b);
  // 5. P @ V
  pv_k<<<8192, 256, 0, stream>>>(S,   qkv + 2 * TCsz,  O);
  pv_k<<<8192, 256, 0, stream>>>(Ssb, qkvs + 2 * TCsz, Os);
  // 6. proj + window-reverse + roll(+3) + residual
  gemm_k<1><<<dim3(4, 784), 256, 0, stream>>>(O,  proj_w,  proj_b,  xr,  x,    256, 256);
  gemm_k<1><<<dim3(4, 784), 256, 0, stream>>>(Os, projs_w, projs_b, xrs, xsar, 256, 256);
  // 7. LN2
  ln2_k<<<kTokens, 256, 0, stream>>>(xr,  ln2_g,  ln2_b,  y);
  ln2_k<<<kTokens, 256, 0, stream>>>(xrs, ln2s_g, ln2s_b, ysb);
  // 8. MLP, token-split halves so hbuf fits in 2 TC
  constexpr size_t HT = (size_t)25088;  // tokens per half
  for (int half = 0; half < 2; ++half) {
    const size_t to = half * HT * 256;       // token offset (x256 ch)
    gemm_k<2><<<dim3(16, 392), 256, 0, stream>>>(y + to,   fc1_w, fc1_b, hbuf, nullptr, 256, 1024);
    gemm_k<3><<<dim3(4, 392), 256, 0, stream>>>(hbuf, fc2_w, fc2_b, out + to, xr + to,  1024, 256);
  }
  for (int half = 0; half < 2; ++half) {
    const size_t to = half * HT * 256;
    gemm_k<2><<<dim3(16, 392), 256, 0, stream>>>(ysb + to, fc1s_w, fc1s_b, hbuf, nullptr, 256, 1024);
    gemm_k<3><<<dim3(4, 392), 256, 0, stream>>>(hbuf, fc2s_w, fc2s_b, out + TCsz + to, xrs + to, 1024, 256);
  }
}

// Round 3
// 1387.961 us; speedup vs baseline: 2.2119x; 2.2119x over previous
//
#include <hip/hip_runtime.h>
#include <hip/hip_bf16.h>
#include <cstdio>

typedef unsigned short ushort_t;
using bf16x8  = __attribute__((ext_vector_type(8))) __bf16;
using floatx4 = __attribute__((ext_vector_type(4))) float;

// Problem constants
constexpr int    kTokens = 50176;                       // B*nW*N = 16*64*49
constexpr size_t TCsz    = (size_t)kTokens * 256;       // 12,845,056 elements
constexpr size_t SSsz    = (size_t)1024 * 8 * 49 * 49;  // 19,668,992 elements
constexpr float  kScale  = 0.17677669529663687f;        // 32^-0.5

// ---------------- block reduce (sum, sumsq) over 256 threads ----------------
__device__ __forceinline__ float2 block_sum2(float s, float s2, float* sbuf) {
#pragma unroll
  for (int off = 32; off > 0; off >>= 1) {
    s  += __shfl_down(s,  off);
    s2 += __shfl_down(s2, off);
  }
  int wv = threadIdx.x >> 6;
  if ((threadIdx.x & 63) == 0) { sbuf[wv * 2] = s; sbuf[wv * 2 + 1] = s2; }
  __syncthreads();
  s  = sbuf[0] + sbuf[2] + sbuf[4] + sbuf[6];
  s2 = sbuf[1] + sbuf[3] + sbuf[5] + sbuf[7];
  return make_float2(s, s2);
}

// ---------------- weight fp32 -> bf16 conversion ----------------
__global__ __launch_bounds__(256) void f2b_k(const float* __restrict__ src,
                                             __hip_bfloat16* __restrict__ dst, int n) {
  int i = blockIdx.x * 256 + threadIdx.x;
  if (i < n) dst[i] = __float2bfloat16(src[i]);
}

// ---------------- LN1 + roll(-3,-3) + window partition -> bf16 ----------------
__global__ __launch_bounds__(256) void pre_ln_k(const float* __restrict__ x,
                                                const float* __restrict__ g,
                                                const float* __restrict__ b,
                                                __hip_bfloat16* __restrict__ xw) {
  __shared__ float sbuf[8];
  int t = blockIdx.x, c = threadIdx.x;
  int bb = t / 3136, r = t % 3136;
  int wi = r / 49, n = r % 49;
  int hp = (wi >> 3) * 7 + n / 7;
  int wp = (wi & 7) * 7 + n % 7;
  int sh = hp + 3; if (sh >= 56) sh -= 56;
  int sw = wp + 3; if (sw >= 56) sw -= 56;
  float v = x[((size_t)bb * 3136 + sh * 56 + sw) * 256 + c];
  float2 ss = block_sum2(v, v * v, sbuf);
  float mean = ss.x * (1.0f / 256.0f);
  float var  = ss.y * (1.0f / 256.0f) - mean * mean;
  float rstd = rsqrtf(var + 1e-5f);
  xw[(size_t)t * 256 + c] = __float2bfloat16((v - mean) * rstd * g[c] + b[c]);
}

// ---------------- LN2 -> bf16 ----------------
__global__ __launch_bounds__(256) void ln2_k(const float* __restrict__ xr,
                                             const float* __restrict__ g,
                                             const float* __restrict__ b,
                                             __hip_bfloat16* __restrict__ y) {
  __shared__ float sbuf[8];
  int t = blockIdx.x, c = threadIdx.x;
  float v = xr[(size_t)t * 256 + c];
  float2 ss = block_sum2(v, v * v, sbuf);
  float mean = ss.x * (1.0f / 256.0f);
  float var  = ss.y * (1.0f / 256.0f) - mean * mean;
  float rstd = rsqrtf(var + 1e-5f);
  y[(size_t)t * 256 + c] = __float2bfloat16((v - mean) * rstd * g[c] + b[c]);
}

// ---------------- bf16 MFMA GEMM: out = A(M x K,bf16) @ W(N x K,bf16)^T ----------------
// 128x128 tile, BK=32, 256 threads (4 waves), each wave 64x64 via 4x4 of 16x16x32 mfma.
// MODE 0: qkv scatter (+bias fp32, q*scale) -> fp32 [which][win*8+head][n][d]
// MODE 1: proj: +bias, window-reverse+roll(+3) scatter, += aux -> fp32
// MODE 2: fc1: +bias, exact GELU -> bf16 [row*Nc+col]
// MODE 3: fc2: +bias, += aux -> fp32 [row*256+col]
template <int MODE>
__global__ __launch_bounds__(256) void bgemm_k(const ushort_t* __restrict__ A,
                                               const ushort_t* __restrict__ W,
                                               const float* __restrict__ bias,
                                               float* __restrict__ outf,
                                               __hip_bfloat16* __restrict__ outb,
                                               const float* __restrict__ aux,
                                               int K, int Nc) {
  __shared__ __align__(16) ushort_t As[4][128][8];  // [k-chunk][m][8 halves]
  __shared__ __align__(16) ushort_t Bs[4][128][8];  // [k-chunk][n][8 halves]
  const int tid  = threadIdx.x;
  const int m0   = blockIdx.y * 128;
  const int n0   = blockIdx.x * 128;
  const int lane = tid & 63, wv = tid >> 6;
  const int wm   = (wv >> 1) * 64, wn = (wv & 1) * 64;
  const int l16  = lane & 15, quad = lane >> 4;
  const int srow = tid >> 2;    // 0..63
  const int skc  = tid & 3;     // k-chunk 0..3

  floatx4 acc[4][4] = {};
  const ushort_t* Ap0 = A + (size_t)(m0 + srow) * K + skc * 8;
  const ushort_t* Ap1 = A + (size_t)(m0 + 64 + srow) * K + skc * 8;
  const ushort_t* Wp0 = W + (size_t)(n0 + srow) * K + skc * 8;
  const ushort_t* Wp1 = W + (size_t)(n0 + 64 + srow) * K + skc * 8;

  for (int k0 = 0; k0 < K; k0 += 32) {
    uint4 a0 = *(const uint4*)(Ap0 + k0);
    uint4 a1 = *(const uint4*)(Ap1 + k0);
    uint4 b0 = *(const uint4*)(Wp0 + k0);
    uint4 b1 = *(const uint4*)(Wp1 + k0);
    *(uint4*)&As[skc][srow][0]      = a0;
    *(uint4*)&As[skc][srow + 64][0] = a1;
    *(uint4*)&Bs[skc][srow][0]      = b0;
    *(uint4*)&Bs[skc][srow + 64][0] = b1;
    __syncthreads();
    bf16x8 af[4], bfr[4];
#pragma unroll
    for (int t = 0; t < 4; ++t) {
      af[t]  = *(const bf16x8*)&As[quad][wm + t * 16 + l16][0];
      bfr[t] = *(const bf16x8*)&Bs[quad][wn + t * 16 + l16][0];
    }
#pragma unroll
    for (int mt = 0; mt < 4; ++mt)
#pragma unroll
      for (int nt = 0; nt < 4; ++nt)
        acc[mt][nt] = __builtin_amdgcn_mfma_f32_16x16x32_bf16(af[mt], bfr[nt], acc[mt][nt], 0, 0, 0);
    __syncthreads();
  }

  // Epilogue. C/D layout: col = lane&15, row = quad*4 + reg   [m89-verified]
#pragma unroll
  for (int nt = 0; nt < 4; ++nt) {
    const int col = n0 + wn + nt * 16 + l16;
    const float bv = bias[col];
#pragma unroll
    for (int mt = 0; mt < 4; ++mt) {
#pragma unroll
      for (int r = 0; r < 4; ++r) {
        const int row = m0 + wm + mt * 16 + quad * 4 + r;
        float val = acc[mt][nt][r] + bv;
        if (MODE == 0) {
          const int which = col >> 8, head = (col >> 5) & 7, d = col & 31;
          if (which == 0) val *= kScale;
          const int wi = row / 49, n = row % 49;
          outf[(size_t)which * TCsz + (size_t)(wi * 8 + head) * 1568 + n * 32 + d] = val;
        } else if (MODE == 1) {
          const int wi = row / 49, n = row % 49;
          const int b = wi >> 6, wl = wi & 63;
          const int hp = (wl >> 3) * 7 + n / 7;
          const int wp = (wl & 7) * 7 + n % 7;
          int h = hp + 3; if (h >= 56) h -= 56;
          int w = wp + 3; if (w >= 56) w -= 56;
          const size_t idx = ((size_t)(b * 3136 + h * 56 + w)) * 256 + col;
          outf[idx] = aux[idx] + val;
        } else if (MODE == 2) {
          val = 0.5f * val * (1.0f + erff(val * 0.70710678118654752f));
          outb[(size_t)row * Nc + col] = __float2bfloat16(val);
        } else {
          const size_t idx = (size_t)row * 256 + col;
          outf[idx] = aux[idx] + val;
        }
      }
    }
  }
}

// ---------------- scores S = q@k^T + rpb + shift-mask, per (win, head) ----------------
__device__ __forceinline__ int lab3(int p) { return p < 49 ? 0 : (p < 53 ? 1 : 2); }

__global__ __launch_bounds__(256) void scores_k(const float* __restrict__ qkv,
                                                const float* __restrict__ rpb,
                                                float* __restrict__ S) {
  __shared__ float ql[49 * 33], kl[49 * 33];
  const int wi = blockIdx.x >> 3, head = blockIdx.x & 7;
  const float* qb = qkv + (size_t)blockIdx.x * 1568;          // q (pre-scaled)
  const float* kb = qkv + TCsz + (size_t)blockIdx.x * 1568;   // k
  for (int e = threadIdx.x; e < 1568; e += 256) {
    int i = e >> 5, d = e & 31;
    ql[i * 33 + d] = qb[e];
    kl[i * 33 + d] = kb[e];
  }
  __syncthreads();
  const int wl = wi & 63, wh = wl >> 3, ww = wl & 7;
  for (int e = threadIdx.x; e < 2401; e += 256) {
    const int i = e / 49, j = e % 49;
    float acc = 0.0f;
#pragma unroll
    for (int d = 0; d < 32; ++d) acc = fmaf(ql[i * 33 + d], kl[j * 33 + d], acc);
    const int yi = i / 7, xi = i % 7, yj = j / 7, xj = j % 7;
    acc += rpb[((yi - yj + 6) * 13 + (xi - xj + 6)) * 8 + head];
    const int li = lab3(wh * 7 + yi) * 3 + lab3(ww * 7 + xi);
    const int lj = lab3(wh * 7 + yj) * 3 + lab3(ww * 7 + xj);
    if (li != lj) acc -= 100.0f;
    S[(size_t)blockIdx.x * 2401 + e] = acc;
  }
}

// ---------------- head-fusion gate + softmax (both branches, in-place) ----------------
__global__ __launch_bounds__(64) void fuse_softmax_k(float* __restrict__ S,
                                                     float* __restrict__ Ss,
                                                     const float* __restrict__ fw,
                                                     const float* __restrict__ fb) {
  __shared__ float s[8][49], ss[8][49];
  const int wi = blockIdx.x / 49, n = blockIdx.x % 49;
  const int tid = threadIdx.x;
  const size_t base = (size_t)wi * 8 * 2401 + (size_t)n * 49;
  for (int e = tid; e < 392; e += 64) {
    const int h = e / 49, m = e % 49;
    s[h][m]  = S[base + (size_t)h * 2401 + m];
    ss[h][m] = Ss[base + (size_t)h * 2401 + m];
  }
  __syncthreads();
  if (tid < 49) {
    const int m = tid;
    float diff[8], logit[8];
#pragma unroll
    for (int h = 0; h < 8; ++h) diff[h] = ss[h][m] - s[h][m];
#pragma unroll
    for (int o = 0; o < 8; ++o) {
      float g = fb[o];
#pragma unroll
      for (int h = 0; h < 8; ++h) g = fmaf(fw[o * 8 + h], diff[h], g);
      g = 1.0f / (1.0f + expf(-g));
      logit[o] = s[o][m] + diff[o] * g;
    }
#pragma unroll
    for (int o = 0; o < 8; ++o) s[o][m] = logit[o];
  }
  __syncthreads();
  const int h = tid >> 3, sub = tid & 7;
  float mx = -1e30f, mxs = -1e30f;
  for (int m = sub; m < 49; m += 8) { mx = fmaxf(mx, s[h][m]); mxs = fmaxf(mxs, ss[h][m]); }
#pragma unroll
  for (int off = 4; off > 0; off >>= 1) {
    mx  = fmaxf(mx,  __shfl_down(mx,  off, 8));
    mxs = fmaxf(mxs, __shfl_down(mxs, off, 8));
  }
  mx  = __shfl(mx, 0, 8);
  mxs = __shfl(mxs, 0, 8);
  float sm = 0.0f, sms = 0.0f;
  for (int m = sub; m < 49; m += 8) { sm += expf(s[h][m] - mx); sms += expf(ss[h][m] - mxs); }
#pragma unroll
  for (int off = 4; off > 0; off >>= 1) {
    sm  += __shfl_down(sm,  off, 8);
    sms += __shfl_down(sms, off, 8);
  }
  sm  = __shfl(sm, 0, 8);
  sms = __shfl(sms, 0, 8);
  const float inv = 1.0f / sm, invs = 1.0f / sms;
  for (int m = sub; m < 49; m += 8) {
    S[base + (size_t)h * 2401 + m]  = expf(s[h][m] - mx) * inv;
    Ss[base + (size_t)h * 2401 + m] = expf(ss[h][m] - mxs) * invs;
  }
}

// ---------------- O = P @ V per (win, head); O stored token-major bf16 ----------------
__global__ __launch_bounds__(256) void pv_k(const float* __restrict__ P,
                                            const float* __restrict__ v,
                                            __hip_bfloat16* __restrict__ O) {
  __shared__ float pl[49 * 49], vl[49 * 32];
  const int wi = blockIdx.x >> 3, head = blockIdx.x & 7;
  const float* Pb = P + (size_t)blockIdx.x * 2401;
  const float* vb = v + (size_t)blockIdx.x * 1568;
  for (int e = threadIdx.x; e < 2401; e += 256) pl[e] = Pb[e];
  for (int e = threadIdx.x; e < 1568; e += 256) vl[e] = vb[e];
  __syncthreads();
  for (int e = threadIdx.x; e < 1568; e += 256) {
    const int nn = e >> 5, d = e & 31;
    float acc = 0.0f;
#pragma unroll
    for (int m = 0; m < 49; ++m) acc = fmaf(pl[nn * 49 + m], vl[m * 32 + d], acc);
    const int t = wi * 49 + nn;
    O[(size_t)t * 256 + head * 32 + d] = __float2bfloat16(acc);
  }
}

extern "C" void kernel_launch(void* const* d_in, const int* in_sizes, int n_in,
                              void* d_out, int out_size, void* d_ws, size_t ws_size,
                              hipStream_t stream) {
  if (n_in < 29) { fprintf(stderr, "kernel_launch: expected 29 inputs, got %d\n", n_in); return; }
  const float* x      = (const float*)d_in[0];
  const float* xsar   = (const float*)d_in[1];
  const float* ln1_g  = (const float*)d_in[2];
  const float* ln1_b  = (const float*)d_in[3];
  const float* ln1s_g = (const float*)d_in[4];
  const float* ln1s_b = (const float*)d_in[5];
  const float* qkv_w  = (const float*)d_in[6];
  const float* qkv_b  = (const float*)d_in[7];
  const float* qkvs_w = (const float*)d_in[8];
  const float* qkvs_b = (const float*)d_in[9];
  const float* rpb    = (const float*)d_in[10];
  const float* fuse_w = (const float*)d_in[11];
  const float* fuse_b = (const float*)d_in[12];
  const float* proj_w = (const float*)d_in[13];
  const float* proj_b = (const float*)d_in[14];
  const float* projs_w = (const float*)d_in[15];
  const float* projs_b = (const float*)d_in[16];
  const float* ln2_g  = (const float*)d_in[17];
  const float* ln2_b  = (const float*)d_in[18];
  const float* ln2s_g = (const float*)d_in[19];
  const float* ln2s_b = (const float*)d_in[20];
  const float* fc1_w  = (const float*)d_in[21];
  const float* fc1_b  = (const float*)d_in[22];
  const float* fc2_w  = (const float*)d_in[23];
  const float* fc2_b  = (const float*)d_in[24];
  const float* fc1s_w = (const float*)d_in[25];
  const float* fc1s_b = (const float*)d_in[26];
  const float* fc2s_w = (const float*)d_in[27];
  const float* fc2s_b = (const float*)d_in[28];
  float* out = (float*)d_out;
  float* ws  = (float*)d_ws;

  const size_t need = 8 * TCsz * sizeof(float);
  if (ws_size < need) {
    fprintf(stderr, "kernel_launch: ws_size %zu < needed %zu\n", ws_size, need);
    return;
  }

  // --- Liveness-packed layout (units of TCsz floats within ws) ---
  // xw/xws (bf16, 0.5 TC each) at [0,1); qkv fp32 [2,5); qkvs fp32 [5,8)
  // S_A -> d_out scratch (1.53 TC <= 2 TC); S_B -> ws floats [0, SSsz)
  // weights bf16 at floats [SSsz, SSsz+0.07TC)   (gap between S_B end and 2TC)
  // O bf16 [2,2.5); Os bf16 [5,5.5); xr [3,4); xrs [6,7)
  // y bf16 [4,4.5); ys bf16 [4.5,5); hbuf bf16 [0,1) (half-M MLP)
  typedef __hip_bfloat16 bf;
  bf* xw    = (bf*)ws;                 // TCsz halves
  bf* xws   = (bf*)ws + TCsz;
  float* qkv  = ws + 2 * TCsz;
  float* qkvs = ws + 5 * TCsz;
  float* S    = out;
  float* Ssb  = ws;
  bf* O     = (bf*)(ws + 2 * TCsz);
  bf* Os    = (bf*)(ws + 5 * TCsz);
  float* xr  = ws + 3 * TCsz;
  float* xrs = ws + 6 * TCsz;
  bf* y     = (bf*)(ws + 4 * TCsz);
  bf* ysb   = (bf*)(ws + 4 * TCsz) + TCsz;
  bf* hbuf  = (bf*)ws;                 // 25088*1024 halves = 1 TC floats
  bf* wb    = (bf*)(ws + SSsz);        // bf16 weights region
  bf* wqkv  = wb;
  bf* wqkvs = wb + 196608;
  bf* wproj = wb + 393216;
  bf* wprojs= wb + 458752;
  bf* wfc1  = wb + 524288;
  bf* wfc1s = wb + 786432;
  bf* wfc2  = wb + 1048576;
  bf* wfc2s = wb + 1310720;

  // 0. convert weights to bf16
  f2b_k<<<768, 256, 0, stream>>>(qkv_w,  wqkv,  196608);
  f2b_k<<<768, 256, 0, stream>>>(qkvs_w, wqkvs, 196608);
  f2b_k<<<256, 256, 0, stream>>>(proj_w, wproj, 65536);
  f2b_k<<<256, 256, 0, stream>>>(projs_w,wprojs,65536);
  f2b_k<<<1024,256, 0, stream>>>(fc1_w,  wfc1,  262144);
  f2b_k<<<1024,256, 0, stream>>>(fc1s_w, wfc1s, 262144);
  f2b_k<<<1024,256, 0, stream>>>(fc2_w,  wfc2,  262144);
  f2b_k<<<1024,256, 0, stream>>>(fc2s_w, wfc2s, 262144);

  // 1. LN1 + shift + window partition (bf16 out)
  pre_ln_k<<<kTokens, 256, 0, stream>>>(x,    ln1_g,  ln1_b,  xw);
  pre_ln_k<<<kTokens, 256, 0, stream>>>(xsar, ln1s_g, ln1s_b, xws);
  // 2. QKV MFMA GEMM (q pre-scaled), scatter fp32 to (win,head,n,d)
  bgemm_k<0><<<dim3(6, 392), 256, 0, stream>>>((const ushort_t*)xw,  (const ushort_t*)wqkv,  qkv_b,  qkv,  nullptr, nullptr, 256, 768);
  bgemm_k<0><<<dim3(6, 392), 256, 0, stream>>>((const ushort_t*)xws, (const ushort_t*)wqkvs, qkvs_b, qkvs, nullptr, nullptr, 256, 768);
  // 3. scores + rpb + shift mask
  scores_k<<<8192, 256, 0, stream>>>(qkv,  rpb, S);
  scores_k<<<8192, 256, 0, stream>>>(qkvs, rpb, Ssb);
  // 4. gate fusion + softmax (in place)
  fuse_softmax_k<<<1024 * 49, 64, 0, stream>>>(S, Ssb, fuse_w, fuse_b);
  // 5. P @ V -> bf16 token-major
  pv_k<<<8192, 256, 0, stream>>>(S,   qkv + 2 * TCsz,  O);
  pv_k<<<8192, 256, 0, stream>>>(Ssb, qkvs + 2 * TCsz, Os);
  // 6. proj MFMA + window-reverse + roll(+3) + residual -> fp32 xr
  bgemm_k<1><<<dim3(2, 392), 256, 0, stream>>>((const ushort_t*)O,  (const ushort_t*)wproj,  proj_b,  xr,  nullptr, x,    256, 256);
  bgemm_k<1><<<dim3(2, 392), 256, 0, stream>>>((const ushort_t*)Os, (const ushort_t*)wprojs, projs_b, xrs, nullptr, xsar, 256, 256);
  // 7. LN2 (bf16 out)
  ln2_k<<<kTokens, 256, 0, stream>>>(xr,  ln2_g,  ln2_b,  y);
  ln2_k<<<kTokens, 256, 0, stream>>>(xrs, ln2s_g, ln2s_b, ysb);
  // 8. MLP (MFMA), token-split halves; hbuf bf16 in [0,1TC)
  constexpr size_t HT = 25088;
  for (int half = 0; half < 2; ++half) {
    const size_t to = half * HT * 256;
    bgemm_k<2><<<dim3(8, 196), 256, 0, stream>>>((const ushort_t*)(y + to), (const ushort_t*)wfc1, fc1_b, nullptr, hbuf, nullptr, 256, 1024);
    bgemm_k<3><<<dim3(2, 196), 256, 0, stream>>>((const ushort_t*)hbuf, (const ushort_t*)wfc2, fc2_b, out + to, nullptr, xr + to, 1024, 256);
  }
  for (int half = 0; half < 2; ++half) {
    const size_t to = half * HT * 256;
    bgemm_k<2><<<dim3(8, 196), 256, 0, stream>>>((const ushort_t*)(ysb + to), (const ushort_t*)wfc1s, fc1s_b, nullptr, hbuf, nullptr, 256, 1024);
    bgemm_k<3><<<dim3(2, 196), 256, 0, stream>>>((const ushort_t*)hbuf, (const ushort_t*)wfc2s, fc2s_b, out + TCsz + to, nullptr, xrs + to, 1024, 256);
  }
}

// Round 4
// 1189.678 us; speedup vs baseline: 2.5806x; 1.1667x over previous
//
#include <hip/hip_runtime.h>
#include <hip/hip_bf16.h>
#include <cstdio>

typedef unsigned short ushort_t;
using bf16x8  = __attribute__((ext_vector_type(8))) __bf16;
using floatx4 = __attribute__((ext_vector_type(4))) float;

// Problem constants
constexpr int    kTokens = 50176;                       // B*nW*N = 16*64*49
constexpr size_t TCsz    = (size_t)kTokens * 256;       // 12,845,056 elements
constexpr size_t SSsz    = (size_t)1024 * 8 * 49 * 49;  // 19,668,992 elements
constexpr float  kScale  = 0.17677669529663687f;        // 32^-0.5

__device__ __forceinline__ float bf2f(ushort_t u) {
  unsigned int x = (unsigned int)u << 16;
  return __uint_as_float(x);
}
__device__ __forceinline__ ushort_t f2bf(float f) {
  __hip_bfloat16 h = __float2bfloat16(f);
  return *(ushort_t*)&h;
}

// ---------------- weight fp32 -> bf16 conversion ----------------
__global__ __launch_bounds__(256) void f2b_k(const float* __restrict__ src,
                                             ushort_t* __restrict__ dst, int n) {
  int i = blockIdx.x * 256 + threadIdx.x;
  if (i < n) dst[i] = f2bf(src[i]);
}

// ---------------- LN (wave per token) + optional roll/window scatter -> bf16 ----------------
// SHIFTED=1: LN1 + roll(-3,-3) + window partition.  SHIFTED=0: LN2 identity.
template <int SHIFTED>
__global__ __launch_bounds__(256) void ln_k(const float* __restrict__ x,
                                            const float* __restrict__ g,
                                            const float* __restrict__ b,
                                            ushort_t* __restrict__ yout) {
  const int wave = threadIdx.x >> 6, lane = threadIdx.x & 63;
  const int t = blockIdx.x * 4 + wave;
  size_t src;
  if (SHIFTED) {
    int bb = t / 3136, r = t % 3136;
    int wi = r / 49, n = r % 49;
    int hp = (wi >> 3) * 7 + n / 7;
    int wp = (wi & 7) * 7 + n % 7;
    int sh = hp + 3; if (sh >= 56) sh -= 56;
    int sw = wp + 3; if (sw >= 56) sw -= 56;
    src = ((size_t)bb * 3136 + sh * 56 + sw) * 256;
  } else {
    src = (size_t)t * 256;
  }
  const float4 v4 = *(const float4*)(x + src + lane * 4);
  float s  = v4.x + v4.y + v4.z + v4.w;
  float s2 = v4.x * v4.x + v4.y * v4.y + v4.z * v4.z + v4.w * v4.w;
#pragma unroll
  for (int off = 32; off > 0; off >>= 1) {
    s  += __shfl_xor(s,  off);
    s2 += __shfl_xor(s2, off);
  }
  const float mean = s * (1.0f / 256.0f);
  const float var  = s2 * (1.0f / 256.0f) - mean * mean;
  const float rstd = rsqrtf(var + 1e-5f);
  const float4 g4 = *(const float4*)(g + lane * 4);
  const float4 b4 = *(const float4*)(b + lane * 4);
  ushort4 o;
  o.x = f2bf((v4.x - mean) * rstd * g4.x + b4.x);
  o.y = f2bf((v4.y - mean) * rstd * g4.y + b4.y);
  o.z = f2bf((v4.z - mean) * rstd * g4.z + b4.z);
  o.w = f2bf((v4.w - mean) * rstd * g4.w + b4.w);
  *(ushort4*)(yout + (size_t)t * 256 + lane * 4) = o;
}

// ---------------- bf16 MFMA GEMM: out = A(M x K,bf16) @ W(N x K,bf16)^T ----------------
// 128x128 tile, BK=32, 256 threads (4 waves), each wave 64x64 via 4x4 of 16x16x32 mfma.
// MODE 0: qkv scatter (+bias, q*scale) -> bf16 [which][win*8+head][n][d]
// MODE 1: proj: +bias, window-reverse+roll(+3) scatter, += aux -> fp32
// MODE 2: fc1: +bias, exact GELU -> bf16 [row*Nc+col]
// MODE 3: fc2: +bias, += aux -> fp32 [row*256+col]
template <int MODE>
__global__ __launch_bounds__(256) void bgemm_k(const ushort_t* __restrict__ A,
                                               const ushort_t* __restrict__ W,
                                               const float* __restrict__ bias,
                                               float* __restrict__ outf,
                                               ushort_t* __restrict__ outb,
                                               const float* __restrict__ aux,
                                               int K, int Nc) {
  __shared__ __align__(16) ushort_t As[4][128][8];
  __shared__ __align__(16) ushort_t Bs[4][128][8];
  const int tid  = threadIdx.x;
  const int m0   = blockIdx.y * 128;
  const int n0   = blockIdx.x * 128;
  const int lane = tid & 63, wv = tid >> 6;
  const int wm   = (wv >> 1) * 64, wn = (wv & 1) * 64;
  const int l16  = lane & 15, quad = lane >> 4;
  const int srow = tid >> 2;
  const int skc  = tid & 3;

  floatx4 acc[4][4] = {};
  const ushort_t* Ap0 = A + (size_t)(m0 + srow) * K + skc * 8;
  const ushort_t* Ap1 = A + (size_t)(m0 + 64 + srow) * K + skc * 8;
  const ushort_t* Wp0 = W + (size_t)(n0 + srow) * K + skc * 8;
  const ushort_t* Wp1 = W + (size_t)(n0 + 64 + srow) * K + skc * 8;

  for (int k0 = 0; k0 < K; k0 += 32) {
    uint4 a0 = *(const uint4*)(Ap0 + k0);
    uint4 a1 = *(const uint4*)(Ap1 + k0);
    uint4 b0 = *(const uint4*)(Wp0 + k0);
    uint4 b1 = *(const uint4*)(Wp1 + k0);
    *(uint4*)&As[skc][srow][0]      = a0;
    *(uint4*)&As[skc][srow + 64][0] = a1;
    *(uint4*)&Bs[skc][srow][0]      = b0;
    *(uint4*)&Bs[skc][srow + 64][0] = b1;
    __syncthreads();
    bf16x8 af[4], bfr[4];
#pragma unroll
    for (int t = 0; t < 4; ++t) {
      af[t]  = *(const bf16x8*)&As[quad][wm + t * 16 + l16][0];
      bfr[t] = *(const bf16x8*)&Bs[quad][wn + t * 16 + l16][0];
    }
#pragma unroll
    for (int mt = 0; mt < 4; ++mt)
#pragma unroll
      for (int nt = 0; nt < 4; ++nt)
        acc[mt][nt] = __builtin_amdgcn_mfma_f32_16x16x32_bf16(af[mt], bfr[nt], acc[mt][nt], 0, 0, 0);
    __syncthreads();
  }

  // C/D layout: col = lane&15, row = quad*4 + reg
#pragma unroll
  for (int nt = 0; nt < 4; ++nt) {
    const int col = n0 + wn + nt * 16 + l16;
    const float bv = bias[col];
#pragma unroll
    for (int mt = 0; mt < 4; ++mt) {
#pragma unroll
      for (int r = 0; r < 4; ++r) {
        const int row = m0 + wm + mt * 16 + quad * 4 + r;
        float val = acc[mt][nt][r] + bv;
        if (MODE == 0) {
          const int which = col >> 8, head = (col >> 5) & 7, d = col & 31;
          if (which == 0) val *= kScale;
          const int wi = row / 49, n = row % 49;
          outb[(size_t)which * TCsz + (size_t)(wi * 8 + head) * 1568 + n * 32 + d] = f2bf(val);
        } else if (MODE == 1) {
          const int wi = row / 49, n = row % 49;
          const int b = wi >> 6, wl = wi & 63;
          const int hp = (wl >> 3) * 7 + n / 7;
          const int wp = (wl & 7) * 7 + n % 7;
          int h = hp + 3; if (h >= 56) h -= 56;
          int w = wp + 3; if (w >= 56) w -= 56;
          const size_t idx = ((size_t)(b * 3136 + h * 56 + w)) * 256 + col;
          outf[idx] = aux[idx] + val;
        } else if (MODE == 2) {
          val = 0.5f * val * (1.0f + erff(val * 0.70710678118654752f));
          outb[(size_t)row * Nc + col] = f2bf(val);
        } else {
          const size_t idx = (size_t)row * 256 + col;
          outf[idx] = aux[idx] + val;
        }
      }
    }
  }
}

// ---------------- scores S = q@k^T + rpb + shift-mask, per (win, head), bf16 io ---------
__device__ __forceinline__ int lab3(int p) { return p < 49 ? 0 : (p < 53 ? 1 : 2); }

__global__ __launch_bounds__(256) void scores_k(const ushort_t* __restrict__ q,
                                                const ushort_t* __restrict__ k,
                                                const float* __restrict__ rpb,
                                                ushort_t* __restrict__ S) {
  __shared__ float ql[49 * 33], kl[49 * 33];
  const int wi = blockIdx.x >> 3, head = blockIdx.x & 7;
  const ushort_t* qb = q + (size_t)blockIdx.x * 1568;
  const ushort_t* kb = k + (size_t)blockIdx.x * 1568;
  for (int e = threadIdx.x; e < 1568; e += 256) {
    int i = e >> 5, d = e & 31;
    ql[i * 33 + d] = bf2f(qb[e]);
    kl[i * 33 + d] = bf2f(kb[e]);
  }
  __syncthreads();
  const int wl = wi & 63, wh = wl >> 3, ww = wl & 7;
  for (int e = threadIdx.x; e < 2401; e += 256) {
    const int i = e / 49, j = e % 49;
    float acc = 0.0f;
#pragma unroll
    for (int d = 0; d < 32; ++d) acc = fmaf(ql[i * 33 + d], kl[j * 33 + d], acc);
    const int yi = i / 7, xi = i % 7, yj = j / 7, xj = j % 7;
    acc += rpb[((yi - yj + 6) * 13 + (xi - xj + 6)) * 8 + head];
    const int li = lab3(wh * 7 + yi) * 3 + lab3(ww * 7 + xi);
    const int lj = lab3(wh * 7 + yj) * 3 + lab3(ww * 7 + xj);
    if (li != lj) acc -= 100.0f;
    S[(size_t)blockIdx.x * 2401 + e] = f2bf(acc);
  }
}

// ---------------- head-fusion gate + softmax, chunked (window, 13-row) blocks ------------
__global__ __launch_bounds__(256) void fuse2_k(ushort_t* __restrict__ S,
                                               ushort_t* __restrict__ Ss,
                                               const float* __restrict__ fw,
                                               const float* __restrict__ fb) {
  __shared__ float s[8][637], ss[8][637];   // 13*49 = 637 ; 40.8 KB total
  __shared__ float fwl[64], fbl[8];
  const int w = blockIdx.x >> 2, ch = blockIdx.x & 3;
  const int n0 = ch * 13;
  const int rows = (n0 + 13 <= 49) ? 13 : (49 - n0);
  const int cnt = 8 * rows * 49;
  const int tid = threadIdx.x;
  if (tid < 64) fwl[tid] = fw[tid];
  if (tid < 8)  fbl[tid] = fb[tid];
  for (int t = tid; t < cnt; t += 256) {
    const int h = t / (rows * 49), rm = t % (rows * 49);
    const size_t gaddr = ((size_t)(w * 8 + h) * 49 + n0) * 49 + rm;
    s[h][rm]  = bf2f(S[gaddr]);
    ss[h][rm] = bf2f(Ss[gaddr]);
  }
  __syncthreads();
  for (int p = tid; p < rows * 49; p += 256) {
    float d[8];
#pragma unroll
    for (int h = 0; h < 8; ++h) d[h] = ss[h][p] - s[h][p];
#pragma unroll
    for (int o = 0; o < 8; ++o) {
      float g = fbl[o];
#pragma unroll
      for (int h = 0; h < 8; ++h) g = fmaf(fwl[o * 8 + h], d[h], g);
      g = 1.0f / (1.0f + expf(-g));
      s[o][p] = s[o][p] + d[o] * g;
    }
  }
  __syncthreads();
  // softmax: one thread per (branch, head, row)
  if (tid < 16 * rows) {
    const int br = tid / (8 * rows);
    const int hr = tid % (8 * rows);
    const int h = hr / rows, r = hr % rows;
    float* row = (br ? ss[h] : s[h]) + r * 49;
    float mx = -1e30f;
    for (int m = 0; m < 49; ++m) mx = fmaxf(mx, row[m]);
    float sum = 0.0f;
    for (int m = 0; m < 49; ++m) { float e = expf(row[m] - mx); row[m] = e; sum += e; }
    const float inv = 1.0f / sum;
    for (int m = 0; m < 49; ++m) row[m] *= inv;
  }
  __syncthreads();
  for (int t = tid; t < cnt; t += 256) {
    const int h = t / (rows * 49), rm = t % (rows * 49);
    const size_t gaddr = ((size_t)(w * 8 + h) * 49 + n0) * 49 + rm;
    S[gaddr]  = f2bf(s[h][rm]);
    Ss[gaddr] = f2bf(ss[h][rm]);
  }
}

// ---------------- O = P @ V per (win, head); all bf16 ----------------
__global__ __launch_bounds__(256) void pv_k(const ushort_t* __restrict__ P,
                                            const ushort_t* __restrict__ v,
                                            ushort_t* __restrict__ O) {
  __shared__ float pl[49 * 49], vl[49 * 32];
  const int wi = blockIdx.x >> 3, head = blockIdx.x & 7;
  const ushort_t* Pb = P + (size_t)blockIdx.x * 2401;
  const ushort_t* vb = v + (size_t)blockIdx.x * 1568;
  for (int e = threadIdx.x; e < 2401; e += 256) pl[e] = bf2f(Pb[e]);
  for (int e = threadIdx.x; e < 1568; e += 256) vl[e] = bf2f(vb[e]);
  __syncthreads();
  for (int e = threadIdx.x; e < 1568; e += 256) {
    const int nn = e >> 5, d = e & 31;
    float acc = 0.0f;
#pragma unroll
    for (int m = 0; m < 49; ++m) acc = fmaf(pl[nn * 49 + m], vl[m * 32 + d], acc);
    const int t = wi * 49 + nn;
    O[(size_t)t * 256 + head * 32 + d] = f2bf(acc);
  }
}

extern "C" void kernel_launch(void* const* d_in, const int* in_sizes, int n_in,
                              void* d_out, int out_size, void* d_ws, size_t ws_size,
                              hipStream_t stream) {
  if (n_in < 29) { fprintf(stderr, "kernel_launch: expected 29 inputs, got %d\n", n_in); return; }
  const float* x      = (const float*)d_in[0];
  const float* xsar   = (const float*)d_in[1];
  const float* ln1_g  = (const float*)d_in[2];
  const float* ln1_b  = (const float*)d_in[3];
  const float* ln1s_g = (const float*)d_in[4];
  const float* ln1s_b = (const float*)d_in[5];
  const float* qkv_w  = (const float*)d_in[6];
  const float* qkv_b  = (const float*)d_in[7];
  const float* qkvs_w = (const float*)d_in[8];
  const float* qkvs_b = (const float*)d_in[9];
  const float* rpb    = (const float*)d_in[10];
  const float* fuse_w = (const float*)d_in[11];
  const float* fuse_b = (const float*)d_in[12];
  const float* proj_w = (const float*)d_in[13];
  const float* proj_b = (const float*)d_in[14];
  const float* projs_w = (const float*)d_in[15];
  const float* projs_b = (const float*)d_in[16];
  const float* ln2_g  = (const float*)d_in[17];
  const float* ln2_b  = (const float*)d_in[18];
  const float* ln2s_g = (const float*)d_in[19];
  const float* ln2s_b = (const float*)d_in[20];
  const float* fc1_w  = (const float*)d_in[21];
  const float* fc1_b  = (const float*)d_in[22];
  const float* fc2_w  = (const float*)d_in[23];
  const float* fc2_b  = (const float*)d_in[24];
  const float* fc1s_w = (const float*)d_in[25];
  const float* fc1s_b = (const float*)d_in[26];
  const float* fc2s_w = (const float*)d_in[27];
  const float* fc2s_b = (const float*)d_in[28];
  float* out = (float*)d_out;
  float* ws  = (float*)d_ws;

  const size_t need = 8 * TCsz * sizeof(float);
  if (ws_size < need) {
    fprintf(stderr, "kernel_launch: ws_size %zu < needed %zu\n", ws_size, need);
    return;
  }

  // --- All-halves (bf16) workspace map; H unit = 1 bf16, 16*TCsz halves total ---
  // xw[0,1TC) xws[1,2TC) | q[2,3) k[3,4) v[4,5) qs[5,6) ks[6,7) vs[7,8) (TC each)
  // SA[8,9.53TC) SB[10,11.53TC) | weights just below 12TC | xr fp32 [6,7)f xrs [7,8)f
  // After liveness: O->xw slot, Os->xws, y->q, ys->k, hbuf->[4,6TC)
  ushort_t* H   = (ushort_t*)ws;
  ushort_t* xw  = H;
  ushort_t* xws = H + TCsz;
  ushort_t* q   = H + 2 * TCsz;   // q,k,v contiguous (which*TCsz offsets)
  ushort_t* qs  = H + 5 * TCsz;
  ushort_t* v_  = H + 4 * TCsz;
  ushort_t* vs  = H + 7 * TCsz;
  ushort_t* SA  = H + 8 * TCsz;
  ushort_t* SB  = H + 10 * TCsz;
  ushort_t* O   = H;
  ushort_t* Os  = H + TCsz;
  float* xr  = ws + 6 * TCsz;
  float* xrs = ws + 7 * TCsz;
  ushort_t* y   = H + 2 * TCsz;
  ushort_t* ysb = H + 3 * TCsz;
  ushort_t* hbuf = H + 4 * TCsz;  // 2 TC halves: full M x 1024
  ushort_t* wb  = H + 12 * TCsz - 1572864;  // bf16 weights, below xr region
  ushort_t* wqkv  = wb;
  ushort_t* wqkvs = wb + 196608;
  ushort_t* wproj = wb + 393216;
  ushort_t* wprojs= wb + 458752;
  ushort_t* wfc1  = wb + 524288;
  ushort_t* wfc1s = wb + 786432;
  ushort_t* wfc2  = wb + 1048576;
  ushort_t* wfc2s = wb + 1310720;

  // 0. convert weights to bf16
  f2b_k<<<768, 256, 0, stream>>>(qkv_w,  wqkv,  196608);
  f2b_k<<<768, 256, 0, stream>>>(qkvs_w, wqkvs, 196608);
  f2b_k<<<256, 256, 0, stream>>>(proj_w, wproj, 65536);
  f2b_k<<<256, 256, 0, stream>>>(projs_w,wprojs,65536);
  f2b_k<<<1024,256, 0, stream>>>(fc1_w,  wfc1,  262144);
  f2b_k<<<1024,256, 0, stream>>>(fc1s_w, wfc1s, 262144);
  f2b_k<<<1024,256, 0, stream>>>(fc2_w,  wfc2,  262144);
  f2b_k<<<1024,256, 0, stream>>>(fc2s_w, wfc2s, 262144);

  // 1. LN1 + shift + window partition (bf16 out), wave-per-token
  ln_k<1><<<12544, 256, 0, stream>>>(x,    ln1_g,  ln1_b,  xw);
  ln_k<1><<<12544, 256, 0, stream>>>(xsar, ln1s_g, ln1s_b, xws);
  // 2. QKV MFMA GEMM (q pre-scaled), scatter bf16 to (win,head,n,d)
  bgemm_k<0><<<dim3(6, 392), 256, 0, stream>>>(xw,  wqkv,  qkv_b,  nullptr, q,  nullptr, 256, 768);
  bgemm_k<0><<<dim3(6, 392), 256, 0, stream>>>(xws, wqkvs, qkvs_b, nullptr, qs, nullptr, 256, 768);
  // 3. scores + rpb + shift mask (bf16 out)
  scores_k<<<8192, 256, 0, stream>>>(q,  q + TCsz,  rpb, SA);
  scores_k<<<8192, 256, 0, stream>>>(qs, qs + TCsz, rpb, SB);
  // 4. gate fusion + softmax (in place, chunked)
  fuse2_k<<<4096, 256, 0, stream>>>(SA, SB, fuse_w, fuse_b);
  // 5. P @ V -> bf16 token-major
  pv_k<<<8192, 256, 0, stream>>>(SA, v_, O);
  pv_k<<<8192, 256, 0, stream>>>(SB, vs, Os);
  // 6. proj MFMA + window-reverse + roll(+3) + residual -> fp32 xr
  bgemm_k<1><<<dim3(2, 392), 256, 0, stream>>>(O,  wproj,  proj_b,  xr,  nullptr, x,    256, 256);
  bgemm_k<1><<<dim3(2, 392), 256, 0, stream>>>(Os, wprojs, projs_b, xrs, nullptr, xsar, 256, 256);
  // 7. LN2 (bf16 out)
  ln_k<0><<<12544, 256, 0, stream>>>(xr,  ln2_g,  ln2_b,  y);
  ln_k<0><<<12544, 256, 0, stream>>>(xrs, ln2s_g, ln2s_b, ysb);
  // 8. MLP (MFMA), full M, hbuf bf16
  bgemm_k<2><<<dim3(8, 392), 256, 0, stream>>>(y,    wfc1,  fc1_b,  nullptr, hbuf, nullptr, 256, 1024);
  bgemm_k<3><<<dim3(2, 392), 256, 0, stream>>>(hbuf, wfc2,  fc2_b,  out,     nullptr, xr,  1024, 256);
  bgemm_k<2><<<dim3(8, 392), 256, 0, stream>>>(ysb,  wfc1s, fc1s_b, nullptr, hbuf, nullptr, 256, 1024);
  bgemm_k<3><<<dim3(2, 392), 256, 0, stream>>>(hbuf, wfc2s, fc2s_b, out + TCsz, nullptr, xrs, 1024, 256);
}